// Round 11
// baseline (422.431 us; speedup 1.0000x reference)
//
#include <hip/hip_runtime.h>
#include <hip/hip_bf16.h>
#include <hip/hip_cooperative_groups.h>

namespace cg = cooperative_groups;

typedef __bf16 bf16_t;
typedef __bf16 bf16x2 __attribute__((ext_vector_type(2)));
typedef __bf16 bf16x4 __attribute__((ext_vector_type(4)));
typedef __bf16 bf16x8 __attribute__((ext_vector_type(8)));
typedef float f32x4 __attribute__((ext_vector_type(4)));
typedef float f32x16 __attribute__((ext_vector_type(16)));
typedef int intx4 __attribute__((ext_vector_type(4)));
typedef unsigned int u32;
typedef unsigned long long u64;

#define S_LEN 2048
#define DM 1024
#define NH 16
#define DK 64
#define M_ROWS 4096
#define SCALE_LOG2E 0.1803368801111204f /* 0.125 * log2(e) */

// 64-col bf16 LDS tile: 8 chunks of 8 elems (16B); phys chunk = chunk ^ (row&7).
__device__ __forceinline__ int sw_off(int row, int col) {
  return row * 64 + ((((col >> 3) ^ row) & 7) << 3) + (col & 7);
}

__device__ __forceinline__ bf16x8 cvt8(const float4& a, const float4& b) {
  bf16x8 v;
  v[0] = (__bf16)a.x; v[1] = (__bf16)a.y; v[2] = (__bf16)a.z; v[3] = (__bf16)a.w;
  v[4] = (__bf16)b.x; v[5] = (__bf16)b.y; v[6] = (__bf16)b.z; v[7] = (__bf16)b.w;
  return v;
}

__device__ __forceinline__ void glds16(const bf16_t* g, bf16_t* l) {
  __builtin_amdgcn_global_load_lds(
      (const __attribute__((address_space(1))) void*)g,
      (__attribute__((address_space(3))) void*)l, 16, 0, 0);
}

// pack two f32 -> u32 of 2 bf16 (lo = first)
__device__ __forceinline__ int pk2(float lo, float hi) {
  bf16x2 t;
  t[0] = (__bf16)lo;
  t[1] = (__bf16)hi;
  return __builtin_bit_cast(int, t);
}

// Cooperative mega-kernel: prep -> gemm_qkv(+Vtw transpose) -> attn -> gemm_out,
// phases separated by grid.sync() instead of 4 kernel launch/drain boundaries
// (R10 analysis: ~100us of the 281us pipeline lives BETWEEN dispatches).
// Grid 256 x 512thr, 64KB LDS union, <=128 VGPR -> 1 block/CU co-resident.
__global__ __launch_bounds__(512, 2) void mega(
    const float* __restrict__ q, const float* __restrict__ k,
    const float* __restrict__ v, const int* __restrict__ mask,
    const float* __restrict__ Wq, const float* __restrict__ bq,
    const float* __restrict__ Wk, const float* __restrict__ bk,
    const float* __restrict__ Wv, const float* __restrict__ bv,
    const float* __restrict__ Wo, const float* __restrict__ bo,
    float* __restrict__ out, void* __restrict__ ws)
{
  __shared__ __align__(16) bf16_t SM[32768];  // 64 KB union for all phases

  const size_t SLICE = (size_t)M_ROWS * DM;
  bf16_t* Xb   = (bf16_t*)ws;                // 3 slices; slice0 re-used as ctx
  bf16_t* QKVb = Xb + 3 * SLICE;             // Q,K slices; slice2 = Vtw
  bf16_t* Wt   = QKVb + 3 * SLICE;
  u64* mbw     = (u64*)(Wt + (size_t)4 * DM * DM);
  bf16_t* ctx  = Xb;
  bf16_t* Vtw  = QKVb + 2 * SLICE;

  const int g = blockIdx.x;
  const int t = threadIdx.x;
  cg::grid_group grid = cg::this_grid();

  // ================= P0: prep (cvt | transw | mask) =================
  {
    // cvt: 12 grid-stride iters, 8 f32->bf16 per thread-iter
    #pragma unroll 2
    for (int it = 0; it < 12; ++it) {
      const int flat = it * 131072 + g * 512 + t;
      const size_t base = (size_t)flat * 8;
      const int z = (int)(base >> 22);               // SLICE = 2^22
      const size_t off = base & ((size_t)(1u << 22) - 1);
      const float* __restrict__ src = (z == 0) ? q : ((z == 1) ? k : v);
      const float4 a = *(const float4*)&src[off];
      const float4 bb = *(const float4*)&src[off + 4];
      *(bf16x8*)&Xb[(size_t)z * SLICE + off] = cvt8(a, bb);
    }
    // transw: 1024 64x64 tiles; block g does tiles 4g..4g+3, two half-blocks
    {
      float* tile = (float*)SM;                      // [2][64][65] f32 = 33.3KB
      const int half = t >> 8, tt = t & 255;
      const int tx = tt & 31, ty = tt >> 5;
      float* myt = tile + half * (64 * 65);
      for (int it = 0; it < 2; ++it) {
        __syncthreads();
        const int tl = g * 4 + it * 2 + half;
        const int z = tl >> 8, rest = tl & 255, by = rest >> 4, bx = rest & 15;
        const float* __restrict__ W =
            (z == 0) ? Wq : ((z == 1) ? Wk : ((z == 2) ? Wv : Wo));
        bf16_t* __restrict__ outw = Wt + (size_t)z * DM * DM;
        const int k0 = bx * 64, n0 = by * 64;
        #pragma unroll
        for (int j = 0; j < 8; ++j) {
          const float2 vv =
              *(const float2*)&W[(size_t)(k0 + ty + 8 * j) * DM + n0 + tx * 2];
          myt[(ty + 8 * j) * 65 + tx * 2] = vv.x;
          myt[(ty + 8 * j) * 65 + tx * 2 + 1] = vv.y;
        }
        __syncthreads();
        #pragma unroll
        for (int j = 0; j < 8; ++j) {
          const int a = ty + 8 * j;
          bf16x2 p;
          p[0] = (__bf16)myt[(tx * 2) * 65 + a];
          p[1] = (__bf16)myt[(tx * 2 + 1) * 65 + a];
          *(bf16x2*)&outw[(size_t)(n0 + a) * DM + k0 + tx * 2] = p;
        }
      }
    }
    // mask: exactly one u64 word per thread (131072 total)
    {
      const int gw = g * 512 + t;                    // b(1)|kw(5)|q(11)
      const int qq = gw & 2047;
      const int kw = (gw >> 11) & 31;
      const int b = gw >> 16;
      const int* src = &mask[((size_t)(b * S_LEN + qq)) * S_LEN + kw * 64];
      u64 bits = 0;
      #pragma unroll
      for (int i = 0; i < 16; ++i) {
        const int4 m4 = *(const int4*)&src[i * 4];
        bits |= (u64)(m4.x != 0) << (4 * i);
        bits |= (u64)(m4.y != 0) << (4 * i + 1);
        bits |= (u64)(m4.z != 0) << (4 * i + 2);
        bits |= (u64)(m4.w != 0) << (4 * i + 3);
      }
      mbw[gw] = bits;
    }
  }
  grid.sync();

  // ============ P1: gemm_qkv, 8 waves/tile, 3 tiles (z=0,1,2) ============
  {
    bf16_t* As = SM;                                 // [128*32]
    bf16_t* Bs = SM + 4096;                          // [128*32]
    const int w = t >> 6, L = t & 63, quad = L >> 4, l16 = L & 15;
    const int mb = 64 * (w & 1), nb = 32 * (w >> 1); // 2x4 wave quadrants
    const int m0 = (g & 31) * 128, n0 = (g >> 5) * 128;
    const int rowS = t >> 2, subS = (t & 3) * 8;     // 512 thr = full 128x32
    for (int z = 0; z < 3; ++z) {
      const bf16_t* __restrict__ A = Xb + (size_t)z * SLICE;
      const bf16_t* __restrict__ Bt = Wt + (size_t)z * DM * DM;
      const float* __restrict__ bias = (z == 0) ? bq : ((z == 1) ? bk : bv);
      f32x4 acc[4][2] = {};
      for (int k0 = 0; k0 < DM; k0 += 32) {
        __syncthreads();
        glds16(&A[(size_t)(m0 + rowS) * DM + k0 + subS], &As[t * 8]);
        glds16(&Bt[(size_t)(n0 + rowS) * DM + k0 + subS], &Bs[t * 8]);
        __syncthreads();
        bf16x8 af[4], bfr[2];
        #pragma unroll
        for (int mt = 0; mt < 4; ++mt)
          af[mt] = *(const bf16x8*)&As[(mb + 16 * mt + l16) * 32 + quad * 8];
        #pragma unroll
        for (int ct = 0; ct < 2; ++ct)
          bfr[ct] = *(const bf16x8*)&Bs[(nb + 16 * ct + l16) * 32 + quad * 8];
        #pragma unroll
        for (int mt = 0; mt < 4; ++mt)
          #pragma unroll
          for (int ct = 0; ct < 2; ++ct)
            acc[mt][ct] = __builtin_amdgcn_mfma_f32_16x16x32_bf16(
                af[mt], bfr[ct], acc[mt][ct], 0, 0, 0);
      }
      if (z < 2) {
        const float scale = (z == 0) ? SCALE_LOG2E : 1.0f;
        bf16_t* __restrict__ outb = QKVb + (size_t)z * SLICE;
        #pragma unroll
        for (int mt = 0; mt < 4; ++mt)
          #pragma unroll
          for (int ct = 0; ct < 2; ++ct)
            #pragma unroll
            for (int r = 0; r < 4; ++r) {
              const int row = m0 + mb + 16 * mt + quad * 4 + r;
              const int n = n0 + nb + 16 * ct + l16;
              outb[(size_t)row * DM + n] =
                  (__bf16)((acc[mt][ct][r] + bias[n]) * scale);
            }
      } else {
        // V: transpose through LDS -> Vtw[bh][dv=64][key=2048]
        __syncthreads();                             // done reading As/Bs
        bf16_t* Ts = SM;                             // [128][136] = 34.8KB
        #pragma unroll
        for (int mt = 0; mt < 4; ++mt)
          #pragma unroll
          for (int ct = 0; ct < 2; ++ct) {
            const int nloc = nb + 16 * ct + l16;
            const int mloc0 = mb + 16 * mt + quad * 4;
            bf16x4 pk4;
            #pragma unroll
            for (int r = 0; r < 4; ++r)
              pk4[r] = (__bf16)(acc[mt][ct][r] + bias[n0 + nloc]);
            *(bf16x4*)&Ts[nloc * 136 + mloc0] = pk4;
          }
        __syncthreads();
        const int nloc = t >> 2, mh = (t & 3) * 32;
        const int n = n0 + nloc, h = n >> 6, dv = n & 63;
        const int b = m0 >> 11, key0 = (m0 & 2047) + mh;
        bf16_t* dst = &Vtw[(((size_t)(b * NH + h)) * DK + dv) * S_LEN + key0];
        #pragma unroll
        for (int j = 0; j < 4; ++j)
          *(bf16x8*)(dst + 8 * j) = *(const bf16x8*)&Ts[nloc * 136 + mh + 8 * j];
      }
    }
  }
  grid.sync();

  // ================= P2: attn (R10-proven structure, 76.9us) =================
  {
    bf16_t (*KVs)[4][4096] = (bf16_t (*)[4][4096]) & SM[0];  // [buf][K0,K1,V0,V1]
    const bf16_t* __restrict__ Qb = QKVb;
    const bf16_t* __restrict__ Kb = QKVb + SLICE;
    const int w = t >> 6, L = t & 63;
    const int l31 = L & 31, h5 = L >> 5;
    const int xcd = g & 7, slot = g >> 3;            // XCD swizzle (R7, -5x HBM)
    const int bh = xcd * 4 + (slot >> 3), qt = slot & 7;
    const int q0 = qt * 256;
    const int b = bh >> 4, h = bh & 15;

    const int qr = q0 + 32 * w + l31;
    bf16x8 qf[4];
    {
      const bf16_t* qsrc = &Qb[(size_t)(b * S_LEN + qr) * DM + h * DK + 8 * h5];
      #pragma unroll
      for (int ks = 0; ks < 4; ++ks) qf[ks] = *(const bf16x8*)(qsrc + 16 * ks);
    }

    const int rk = t >> 3;
    const int ck = (t & 7) ^ (rk & 7);
    const bf16_t* pK = &Kb[(size_t)(b * S_LEN + rk) * DM + h * DK + ck * 8];
    const bf16_t* pV = &Vtw[((size_t)bh * DK + rk) * S_LEN + ck * 8];
    const u64* pm = &mbw[(size_t)b * 32 * S_LEN + qr];

    f32x16 O[2] = {};
    float l_lane = 0.f;

    auto compute = [&](const bf16_t* __restrict__ Kc,
                       const bf16_t* __restrict__ Vc, u64 mcur) {
      f32x16 s0 = {}, s1 = {};
      #pragma unroll
      for (int ks = 0; ks < 4; ++ks) {
        const bf16x8 kf0 = *(const bf16x8*)&Kc[sw_off(l31, ks * 16 + 8 * h5)];
        const bf16x8 kf1 = *(const bf16x8*)&Kc[sw_off(32 + l31, ks * 16 + 8 * h5)];
        s0 = __builtin_amdgcn_mfma_f32_32x32x16_bf16(kf0, qf[ks], s0, 0, 0, 0);
        s1 = __builtin_amdgcn_mfma_f32_32x32x16_bf16(kf1, qf[ks], s1, 0, 0, 0);
      }
      #pragma unroll
      for (int nt = 0; nt < 2; ++nt) {
        const u32 mm = ((u32)(mcur >> (nt ? 32 : 0))) >> (4 * h5);
        const f32x16 sacc = nt ? s1 : s0;
        float p[16];
        #pragma unroll
        for (int r = 0; r < 16; ++r) {
          const int cb = (r & 3) + 8 * (r >> 2);
          const u32 mr = (u32)(((int)(mm << (31 - cb))) >> 31);
          const float e = __builtin_exp2f(sacc[r]);
          const float pv = __builtin_bit_cast(float, __builtin_bit_cast(u32, e) & mr);
          l_lane += pv;
          p[r] = pv;
        }
        #pragma unroll
        for (int ss = 0; ss < 2; ++ss) {
          const int x0 = pk2(p[8 * ss + 0], p[8 * ss + 1]);
          const int x1 = pk2(p[8 * ss + 2], p[8 * ss + 3]);
          const int y0 = pk2(p[8 * ss + 4], p[8 * ss + 5]);
          const int y1 = pk2(p[8 * ss + 6], p[8 * ss + 7]);
          const auto r0 = __builtin_amdgcn_permlane32_swap(x0, y0, false, false);
          const auto r1 = __builtin_amdgcn_permlane32_swap(x1, y1, false, false);
          intx4 wv;
          wv[0] = r0[0]; wv[1] = r1[0]; wv[2] = r0[1]; wv[3] = r1[1];
          const bf16x8 pf = __builtin_bit_cast(bf16x8, wv);
          const int s4 = 2 * nt + ss;
          const bf16x8 vf0 = *(const bf16x8*)&Vc[sw_off(l31, s4 * 16 + 8 * h5)];
          const bf16x8 vf1 = *(const bf16x8*)&Vc[sw_off(32 + l31, s4 * 16 + 8 * h5)];
          O[0] = __builtin_amdgcn_mfma_f32_32x32x16_bf16(vf0, pf, O[0], 0, 0, 0);
          O[1] = __builtin_amdgcn_mfma_f32_32x32x16_bf16(vf1, pf, O[1], 0, 0, 0);
        }
      }
    };

    bf16x8 k0r = *(const bf16x8*)pK;
    bf16x8 k1r = *(const bf16x8*)(pK + (size_t)64 * DM);
    bf16x8 v0r = *(const bf16x8*)pV;
    bf16x8 v1r = *(const bf16x8*)(pV + 64);
    u64 m0 = pm[0], m1 = pm[S_LEN];
    pK += (size_t)128 * DM; pV += 128; pm += 2 * S_LEN;
    *(bf16x8*)&KVs[0][0][t * 8] = k0r;
    *(bf16x8*)&KVs[0][1][t * 8] = k1r;
    *(bf16x8*)&KVs[0][2][t * 8] = v0r;
    *(bf16x8*)&KVs[0][3][t * 8] = v1r;
    __syncthreads();

    for (int kt = 0; kt < S_LEN / 128; ++kt) {
      const int cur = kt & 1;
      u64 n0 = 0, n1 = 0;
      if (kt + 1 < S_LEN / 128) {
        k0r = *(const bf16x8*)pK;
        k1r = *(const bf16x8*)(pK + (size_t)64 * DM);
        v0r = *(const bf16x8*)pV;
        v1r = *(const bf16x8*)(pV + 64);
        n0 = pm[0]; n1 = pm[S_LEN];
        pK += (size_t)128 * DM; pV += 128; pm += 2 * S_LEN;
      }
      compute(&KVs[cur][0][0], &KVs[cur][2][0], m0);
      compute(&KVs[cur][1][0], &KVs[cur][3][0], m1);
      if (kt + 1 < S_LEN / 128) {
        *(bf16x8*)&KVs[cur ^ 1][0][t * 8] = k0r;
        *(bf16x8*)&KVs[cur ^ 1][1][t * 8] = k1r;
        *(bf16x8*)&KVs[cur ^ 1][2][t * 8] = v0r;
        *(bf16x8*)&KVs[cur ^ 1][3][t * 8] = v1r;
        m0 = n0; m1 = n1;
      }
      __syncthreads();
    }

    const float lsum = l_lane + __shfl_xor(l_lane, 32);
    const float inv = 1.f / lsum;
    bf16_t* sc = &SM[0] + (size_t)w * 2048;
    #pragma unroll
    for (int ot = 0; ot < 2; ++ot)
      #pragma unroll
      for (int r = 0; r < 16; ++r) {
        const int dv = 32 * ot + (r & 3) + 8 * (r >> 2) + 4 * h5;
        sc[sw_off(l31, dv)] = (__bf16)(O[ot][r] * inv);
      }
    const int erow = L >> 1, ecol = (L & 1) * 32;
    bf16_t* dst =
        &ctx[(size_t)(b * S_LEN + q0 + 32 * w + erow) * DM + h * DK + ecol];
    #pragma unroll
    for (int c8 = 0; c8 < 4; ++c8)
      *(bf16x8*)(dst + 8 * c8) = *(const bf16x8*)&sc[sw_off(erow, ecol + 8 * c8)];
  }
  grid.sync();

  // ================= P3: gemm_out, 8 waves, one 128x128 tile =================
  {
    bf16_t* As = SM;
    bf16_t* Bs = SM + 4096;
    const bf16_t* __restrict__ A = ctx;
    const bf16_t* __restrict__ Bt = Wt + (size_t)3 * DM * DM;
    const int w = t >> 6, L = t & 63, quad = L >> 4, l16 = L & 15;
    const int mb = 64 * (w & 1), nb = 32 * (w >> 1);
    const int m0 = (g & 31) * 128, n0 = (g >> 5) * 128;
    const int rowS = t >> 2, subS = (t & 3) * 8;
    f32x4 acc[4][2] = {};
    for (int k0 = 0; k0 < DM; k0 += 32) {
      __syncthreads();
      glds16(&A[(size_t)(m0 + rowS) * DM + k0 + subS], &As[t * 8]);
      glds16(&Bt[(size_t)(n0 + rowS) * DM + k0 + subS], &Bs[t * 8]);
      __syncthreads();
      bf16x8 af[4], bfr[2];
      #pragma unroll
      for (int mt = 0; mt < 4; ++mt)
        af[mt] = *(const bf16x8*)&As[(mb + 16 * mt + l16) * 32 + quad * 8];
      #pragma unroll
      for (int ct = 0; ct < 2; ++ct)
        bfr[ct] = *(const bf16x8*)&Bs[(nb + 16 * ct + l16) * 32 + quad * 8];
      #pragma unroll
      for (int mt = 0; mt < 4; ++mt)
        #pragma unroll
        for (int ct = 0; ct < 2; ++ct)
          acc[mt][ct] = __builtin_amdgcn_mfma_f32_16x16x32_bf16(
              af[mt], bfr[ct], acc[mt][ct], 0, 0, 0);
    }
    #pragma unroll
    for (int mt = 0; mt < 4; ++mt)
      #pragma unroll
      for (int ct = 0; ct < 2; ++ct)
        #pragma unroll
        for (int r = 0; r < 4; ++r) {
          const int row = m0 + mb + 16 * mt + quad * 4 + r;
          const int n = n0 + nb + 16 * ct + l16;
          out[(size_t)row * DM + n] = acc[mt][ct][r] + bo[n];
        }
  }
}

extern "C" void kernel_launch(void* const* d_in, const int* in_sizes, int n_in,
                              void* d_out, int out_size, void* d_ws, size_t ws_size,
                              hipStream_t stream) {
  const float* q  = (const float*)d_in[0];
  const float* k  = (const float*)d_in[1];
  const float* v  = (const float*)d_in[2];
  const int* mask = (const int*)d_in[3];
  const float* Wq = (const float*)d_in[4];
  const float* bq = (const float*)d_in[5];
  const float* Wk = (const float*)d_in[6];
  const float* bk = (const float*)d_in[7];
  const float* Wv = (const float*)d_in[8];
  const float* bv = (const float*)d_in[9];
  const float* Wo = (const float*)d_in[10];
  const float* bo = (const float*)d_in[11];
  float* out = (float*)d_out;
  void* ws = d_ws;

  void* args[] = {
      (void*)&q,  (void*)&k,  (void*)&v,  (void*)&mask,
      (void*)&Wq, (void*)&bq, (void*)&Wk, (void*)&bk,
      (void*)&Wv, (void*)&bv, (void*)&Wo, (void*)&bo,
      (void*)&out, (void*)&ws};
  hipLaunchCooperativeKernel((void*)mega, dim3(256), dim3(512), args, 0, stream);
}

// Round 12
// 279.512 us; speedup vs baseline: 1.5113x; 1.5113x over previous
//
#include <hip/hip_runtime.h>
#include <hip/hip_bf16.h>

typedef __bf16 bf16_t;
typedef __bf16 bf16x2 __attribute__((ext_vector_type(2)));
typedef __bf16 bf16x4 __attribute__((ext_vector_type(4)));
typedef __bf16 bf16x8 __attribute__((ext_vector_type(8)));
typedef float f32x4 __attribute__((ext_vector_type(4)));
typedef float f32x16 __attribute__((ext_vector_type(16)));
typedef int intx4 __attribute__((ext_vector_type(4)));
typedef unsigned int u32;
typedef unsigned long long u64;

#define S_LEN 2048
#define DM 1024
#define NH 16
#define DK 64
#define M_ROWS 4096
#define SCALE_LOG2E 0.1803368801111204f /* 0.125 * log2(e) */

// 64-col bf16 LDS tile: 8 chunks of 8 elems (16B); phys chunk = chunk ^ (row&7).
__device__ __forceinline__ int sw_off(int row, int col) {
  return row * 64 + ((((col >> 3) ^ row) & 7) << 3) + (col & 7);
}

__device__ __forceinline__ bf16x8 cvt8(const float4& a, const float4& b) {
  bf16x8 v;
  v[0] = (__bf16)a.x; v[1] = (__bf16)a.y; v[2] = (__bf16)a.z; v[3] = (__bf16)a.w;
  v[4] = (__bf16)b.x; v[5] = (__bf16)b.y; v[6] = (__bf16)b.z; v[7] = (__bf16)b.w;
  return v;
}

__device__ __forceinline__ void glds16(const bf16_t* g, bf16_t* l) {
  __builtin_amdgcn_global_load_lds(
      (const __attribute__((address_space(1))) void*)g,
      (__attribute__((address_space(3))) void*)l, 16, 0, 0);
}

// pack two f32 -> u32 of 2 bf16 (lo = first)
__device__ __forceinline__ int pk2(float lo, float hi) {
  bf16x2 t;
  t[0] = (__bf16)lo;
  t[1] = (__bf16)hi;
  return __builtin_bit_cast(int, t);
}

// Fused prep: [0,6144) cvt_inputs | [6144,7168) transw | [7168,7680) pack_mask.
__global__ __launch_bounds__(256) void prep(
    const float* __restrict__ q, const float* __restrict__ k,
    const float* __restrict__ v, bf16_t* __restrict__ Xb,
    const float* __restrict__ Wq, const float* __restrict__ Wk,
    const float* __restrict__ Wv, const float* __restrict__ Wo,
    bf16_t* __restrict__ Wt,
    const int* __restrict__ mask, u64* __restrict__ mb)
{
  __shared__ float tile[64][65];
  const int blk = blockIdx.x;
  if (blk < 6144) {
    // q,k,v fp32 -> Xb bf16 [3][4096][1024]
    const int z = blk >> 11;
    const int bx = blk & 2047;
    const float* __restrict__ src = (z == 0) ? q : ((z == 1) ? k : v);
    const size_t idx = ((size_t)bx * 256 + threadIdx.x) * 8;
    const float4 a = *(const float4*)&src[idx];
    const float4 b = *(const float4*)&src[idx + 4];
    *(bf16x8*)&Xb[(size_t)z * M_ROWS * DM + idx] = cvt8(a, b);
  } else if (blk < 7168) {
    // W fp32 [k][n] -> Wt bf16 [n][k]
    const int idx = blk - 6144;
    const int z = idx >> 8, by = (idx >> 4) & 15, bx = idx & 15;
    const float* __restrict__ W = (z == 0) ? Wq : ((z == 1) ? Wk : ((z == 2) ? Wv : Wo));
    bf16_t* __restrict__ out = Wt + (size_t)z * DM * DM;
    const int tx = threadIdx.x & 31, ty = threadIdx.x >> 5;
    const int k0 = bx * 64, n0 = by * 64;
    #pragma unroll
    for (int j = 0; j < 8; ++j) {
      const float2 vv = *(const float2*)&W[(size_t)(k0 + ty + 8 * j) * DM + n0 + tx * 2];
      tile[ty + 8 * j][tx * 2] = vv.x;
      tile[ty + 8 * j][tx * 2 + 1] = vv.y;
    }
    __syncthreads();
    #pragma unroll
    for (int j = 0; j < 8; ++j) {
      const int a = ty + 8 * j;
      bf16x2 p;
      p[0] = (__bf16)tile[tx * 2][a];
      p[1] = (__bf16)tile[tx * 2 + 1][a];
      *(bf16x2*)&out[(size_t)(n0 + a) * DM + k0 + tx * 2] = p;
    }
  } else {
    // mask int32 [B,1,S,S] -> row-packed u64: mb[(b*32+kw)*2048+q],
    // bit i = mask[b][q][kw*64+i]
    const int g = (blk - 7168) * 256 + threadIdx.x;  // b(1)|kw(5)|q(11)
    const int qq = g & 2047;
    const int kw = (g >> 11) & 31;
    const int b = g >> 16;
    const int* src = &mask[((size_t)(b * S_LEN + qq)) * S_LEN + kw * 64];
    u64 bits = 0;
    #pragma unroll
    for (int i = 0; i < 16; ++i) {
      const int4 m4 = *(const int4*)&src[i * 4];
      bits |= (u64)(m4.x != 0) << (4 * i);
      bits |= (u64)(m4.y != 0) << (4 * i + 1);
      bits |= (u64)(m4.z != 0) << (4 * i + 2);
      bits |= (u64)(m4.w != 0) << (4 * i + 3);
    }
    mb[g] = bits;
  }
}

// m97-style 128x128 BK=32 BT-GEMM (R0-R10 proven): C = (A @ Bt^T + bias)*scale.
// m0/n0 passed in (caller does panel-XCD remapping). Output modes: outb (bf16),
// outf (fp32), or vtw: transposed-through-LDS write to Vtw[bh][dv][key].
__device__ __forceinline__ void gemm128_body(
    const bf16_t* __restrict__ A, const bf16_t* __restrict__ Bt,
    const float* __restrict__ bias, const float scale,
    bf16_t* __restrict__ outb, float* __restrict__ outf,
    bf16_t* __restrict__ vtw, const int m0, const int n0)
{
  // Smem: As = [0,4096), Bs = [4096,8192); transpose scratch (128x136 bf16,
  // pad 8 -> rows 272B = 16B-aligned) reuses the whole buffer.
  __shared__ __align__(16) bf16_t Smem[128 * 136];
  bf16_t* As = Smem;
  bf16_t* Bs = Smem + 4096;
  const int t = threadIdx.x, w = t >> 6, L = t & 63, quad = L >> 4, l16 = L & 15;
  const int mb = 64 * (w & 1), nb = 64 * (w >> 1);
  const int rowS = t >> 2, subS = (t & 3) * 8;

  f32x4 acc[4][4] = {};
  for (int k0 = 0; k0 < DM; k0 += 32) {
    __syncthreads();
    glds16(&A[(size_t)(m0 + rowS) * DM + k0 + subS],        &As[t * 8]);
    glds16(&A[(size_t)(m0 + 64 + rowS) * DM + k0 + subS],   &As[2048 + t * 8]);
    glds16(&Bt[(size_t)(n0 + rowS) * DM + k0 + subS],       &Bs[t * 8]);
    glds16(&Bt[(size_t)(n0 + 64 + rowS) * DM + k0 + subS],  &Bs[2048 + t * 8]);
    __syncthreads();
    bf16x8 af[4], bfr[4];
    #pragma unroll
    for (int mt = 0; mt < 4; ++mt)
      af[mt] = *(const bf16x8*)&As[(mb + 16 * mt + l16) * 32 + quad * 8];
    #pragma unroll
    for (int ct = 0; ct < 4; ++ct)
      bfr[ct] = *(const bf16x8*)&Bs[(nb + 16 * ct + l16) * 32 + quad * 8];
    #pragma unroll
    for (int mt = 0; mt < 4; ++mt)
      #pragma unroll
      for (int ct = 0; ct < 4; ++ct)
        acc[mt][ct] = __builtin_amdgcn_mfma_f32_16x16x32_bf16(af[mt], bfr[ct], acc[mt][ct], 0, 0, 0);
  }

  if (vtw) {
    // V path: write transposed to Vtw[bh][dv=64][key=2048], coalesced.
    __syncthreads();  // all waves done reading As/Bs
    #pragma unroll
    for (int mt = 0; mt < 4; ++mt)
      #pragma unroll
      for (int ct = 0; ct < 4; ++ct) {
        const int nloc = nb + 16 * ct + l16;
        const int mloc0 = mb + 16 * mt + quad * 4;
        bf16x4 pk;
        #pragma unroll
        for (int r = 0; r < 4; ++r)
          pk[r] = (__bf16)(acc[mt][ct][r] + bias[n0 + nloc]);
        *(bf16x4*)&Smem[nloc * 136 + mloc0] = pk;
      }
    __syncthreads();
    const int nloc = t >> 1, mh = (t & 1) * 64;
    const int n = n0 + nloc, h = n >> 6, dv = n & 63;
    const int b = m0 >> 11, key0 = (m0 & 2047) + mh;
    bf16_t* dst = &vtw[(((size_t)(b * NH + h)) * DK + dv) * S_LEN + key0];
    #pragma unroll
    for (int j = 0; j < 8; ++j)
      *(bf16x8*)(dst + 8 * j) = *(const bf16x8*)&Smem[nloc * 136 + mh + 8 * j];
    return;
  }

  #pragma unroll
  for (int mt = 0; mt < 4; ++mt)
    #pragma unroll
    for (int ct = 0; ct < 4; ++ct)
      #pragma unroll
      for (int r = 0; r < 4; ++r) {
        const int row = m0 + mb + 16 * mt + quad * 4 + r;
        const int n = n0 + nb + 16 * ct + l16;
        const float val = (acc[mt][ct][r] + bias[n]) * scale;
        if (outb) outb[(size_t)row * DM + n] = (__bf16)val;
        else      outf[(size_t)row * DM + n] = val;
      }
}

// gemm_qkv: 768 blocks, panel-XCD remap. bid = m*24 + p (p = z*8+y panel id),
// so bid%8 = p%8 -> all 32 m-tiles of one Bt panel land on ONE XCD L2
// (default round-robin duplicated each 256KB panel across all 8 XCDs: ~48MB
// of dup panel traffic; remap -> ~6MB). Pure bijective remap.
__global__ __launch_bounds__(256) void gemm_qkv(
    const bf16_t* __restrict__ Xb, const bf16_t* __restrict__ Wt,
    const float* __restrict__ bq, const float* __restrict__ bk,
    const float* __restrict__ bv, bf16_t* __restrict__ QKVb,
    bf16_t* __restrict__ Vtw)
{
  const int bid = blockIdx.x;
  const int p = bid % 24, m = bid / 24;
  const int z = p >> 3, y = p & 7;
  // Q slice pre-scaled by 0.125*log2(e); V slice (z=2) straight to Vtw transposed.
  gemm128_body(Xb + (size_t)z * M_ROWS * DM, Wt + (size_t)z * DM * DM,
               (z == 0) ? bq : ((z == 1) ? bk : bv),
               (z == 0) ? SCALE_LOG2E : 1.0f,
               (z == 2) ? nullptr : QKVb + (size_t)z * M_ROWS * DM, nullptr,
               (z == 2) ? Vtw : nullptr, m * 128, y * 128);
}

// gemm_out: 64x128 tiles, 512 blocks (2/CU), panel-XCD remap: bid = m*8 + y
// -> bid%8 = y, panel y resident on one XCD.
__global__ __launch_bounds__(256) void gemm_out(
    const bf16_t* __restrict__ A, const bf16_t* __restrict__ Bt,
    const float* __restrict__ bias, float* __restrict__ outf)
{
  __shared__ __align__(16) bf16_t As[64 * 32];
  __shared__ __align__(16) bf16_t Bs[128 * 32];
  const int t = threadIdx.x, w = t >> 6, L = t & 63, quad = L >> 4, l16 = L & 15;
  const int bid = blockIdx.x;
  const int m0 = (bid >> 3) * 64, n0 = (bid & 7) * 128;
  const int nb = 32 * w;
  const int rowS = t >> 2, subS = (t & 3) * 8;

  f32x4 acc[4][2] = {};
  for (int k0 = 0; k0 < DM; k0 += 32) {
    __syncthreads();
    glds16(&A[(size_t)(m0 + rowS) * DM + k0 + subS],        &As[t * 8]);
    glds16(&Bt[(size_t)(n0 + rowS) * DM + k0 + subS],       &Bs[t * 8]);
    glds16(&Bt[(size_t)(n0 + 64 + rowS) * DM + k0 + subS],  &Bs[2048 + t * 8]);
    __syncthreads();
    bf16x8 af[4], bfr[2];
    #pragma unroll
    for (int mt = 0; mt < 4; ++mt)
      af[mt] = *(const bf16x8*)&As[(16 * mt + l16) * 32 + quad * 8];
    #pragma unroll
    for (int ct = 0; ct < 2; ++ct)
      bfr[ct] = *(const bf16x8*)&Bs[(nb + 16 * ct + l16) * 32 + quad * 8];
    #pragma unroll
    for (int mt = 0; mt < 4; ++mt)
      #pragma unroll
      for (int ct = 0; ct < 2; ++ct)
        acc[mt][ct] = __builtin_amdgcn_mfma_f32_16x16x32_bf16(af[mt], bfr[ct], acc[mt][ct], 0, 0, 0);
  }
  #pragma unroll
  for (int mt = 0; mt < 4; ++mt)
    #pragma unroll
    for (int ct = 0; ct < 2; ++ct)
      #pragma unroll
      for (int r = 0; r < 4; ++r) {
        const int row = m0 + 16 * mt + quad * 4 + r;
        const int n = n0 + nb + 16 * ct + l16;
        outf[(size_t)row * DM + n] = acc[mt][ct][r] + bias[n];
      }
}

// Flash attention (R10-proven, best measured: 76.9us, FETCH 14.4MB) — UNCHANGED:
// QBLK=256, 8 waves, KVBLK=128 (2x64 subtiles), reg-staged write-late dbuf,
// one barrier per 128 keys, XCD swizzle (8 q-tiles of one bh share an XCD L2),
// prescaled-Q exp2 softmax, sign-extend-AND mask, VALU l-accum, no setprio.
__global__ __launch_bounds__(512, 2) void attn_kernel(
    const bf16_t* __restrict__ Qb, const bf16_t* __restrict__ Kb,
    const bf16_t* __restrict__ Vtw, const u64* __restrict__ mb,
    bf16_t* __restrict__ ctx)
{
  __shared__ __align__(16) bf16_t KVs[2][4][64 * 64];  // [buf][K0,K1,V0,V1] 64KB

  const int t = threadIdx.x, w = t >> 6, L = t & 63;
  const int l31 = L & 31, h5 = L >> 5;
  // XCD swizzle: xcd = g&7 owns bh in [4*xcd, 4*xcd+4) (2MB K/V fits 4MB L2)
  const int g = blockIdx.x;
  const int xcd = g & 7, slot = g >> 3;
  const int bh = xcd * 4 + (slot >> 3), qt = slot & 7;
  const int q0 = qt * 256;
  const int b = bh >> 4, h = bh & 15;

  // Q fragments: one-time direct gather (rows q0+32w+l31)
  const int qr = q0 + 32 * w + l31;
  bf16x8 qf[4];
  {
    const bf16_t* qsrc = &Qb[(size_t)(b * S_LEN + qr) * DM + h * DK + 8 * h5];
    #pragma unroll
    for (int ks = 0; ks < 4; ++ks) qf[ks] = *(const bf16x8*)(qsrc + 16 * ks);
  }

  // staging: thread t handles row rk = t>>3 of each 64-row subtile, 16B chunk.
  // dest = t*8 (linear); source chunk ck pre-applies the sw_off XOR.
  const int rk = t >> 3;
  const int ck = (t & 7) ^ (rk & 7);
  const bf16_t* pK = &Kb[(size_t)(b * S_LEN + rk) * DM + h * DK + ck * 8];
  const bf16_t* pV = &Vtw[((size_t)bh * DK + rk) * S_LEN + ck * 8];
  const u64* pm = &mb[(size_t)b * 32 * S_LEN + qr];

  f32x16 O[2] = {};
  float l_lane = 0.f;

  auto compute = [&](const bf16_t* __restrict__ Kc, const bf16_t* __restrict__ Vc,
                     u64 mcur) {
    f32x16 s0 = {}, s1 = {};
    #pragma unroll
    for (int ks = 0; ks < 4; ++ks) {
      const bf16x8 kf0 = *(const bf16x8*)&Kc[sw_off(l31, ks * 16 + 8 * h5)];
      const bf16x8 kf1 = *(const bf16x8*)&Kc[sw_off(32 + l31, ks * 16 + 8 * h5)];
      s0 = __builtin_amdgcn_mfma_f32_32x32x16_bf16(kf0, qf[ks], s0, 0, 0, 0);
      s1 = __builtin_amdgcn_mfma_f32_32x32x16_bf16(kf1, qf[ks], s1, 0, 0, 0);
    }
    #pragma unroll
    for (int nt = 0; nt < 2; ++nt) {
      const u32 mm = ((u32)(mcur >> (nt ? 32 : 0))) >> (4 * h5);
      const f32x16 sacc = nt ? s1 : s0;
      float p[16];
      #pragma unroll
      for (int r = 0; r < 16; ++r) {
        const int cb = (r & 3) + 8 * (r >> 2);
        const u32 mr = (u32)(((int)(mm << (31 - cb))) >> 31);
        const float e = __builtin_exp2f(sacc[r]);
        const float pv = __builtin_bit_cast(float, __builtin_bit_cast(u32, e) & mr);
        l_lane += pv;
        p[r] = pv;
      }
      #pragma unroll
      for (int ss = 0; ss < 2; ++ss) {
        const int x0 = pk2(p[8 * ss + 0], p[8 * ss + 1]);
        const int x1 = pk2(p[8 * ss + 2], p[8 * ss + 3]);
        const int y0 = pk2(p[8 * ss + 4], p[8 * ss + 5]);
        const int y1 = pk2(p[8 * ss + 6], p[8 * ss + 7]);
        const auto r0 = __builtin_amdgcn_permlane32_swap(x0, y0, false, false);
        const auto r1 = __builtin_amdgcn_permlane32_swap(x1, y1, false, false);
        intx4 wv;
        wv[0] = r0[0]; wv[1] = r1[0]; wv[2] = r0[1]; wv[3] = r1[1];
        const bf16x8 pf = __builtin_bit_cast(bf16x8, wv);
        const int s4 = 2 * nt + ss;  // 16-key slot within the 64-key subtile
        const bf16x8 vf0 = *(const bf16x8*)&Vc[sw_off(l31, s4 * 16 + 8 * h5)];
        const bf16x8 vf1 = *(const bf16x8*)&Vc[sw_off(32 + l31, s4 * 16 + 8 * h5)];
        O[0] = __builtin_amdgcn_mfma_f32_32x32x16_bf16(vf0, pf, O[0], 0, 0, 0);
        O[1] = __builtin_amdgcn_mfma_f32_32x32x16_bf16(vf1, pf, O[1], 0, 0, 0);
      }
    }
  };

  // prologue: load + write tile 0 (two 64-key subtiles)
  bf16x8 k0r = *(const bf16x8*)pK;
  bf16x8 k1r = *(const bf16x8*)(pK + (size_t)64 * DM);
  bf16x8 v0r = *(const bf16x8*)pV;
  bf16x8 v1r = *(const bf16x8*)(pV + 64);
  u64 m0 = pm[0], m1 = pm[S_LEN];
  pK += (size_t)128 * DM; pV += 128; pm += 2 * S_LEN;
  *(bf16x8*)&KVs[0][0][t * 8] = k0r;
  *(bf16x8*)&KVs[0][1][t * 8] = k1r;
  *(bf16x8*)&KVs[0][2][t * 8] = v0r;
  *(bf16x8*)&KVs[0][3][t * 8] = v1r;
  __syncthreads();

  for (int kt = 0; kt < S_LEN / 128; ++kt) {
    const int cur = kt & 1;
    u64 n0 = 0, n1 = 0;
    if (kt + 1 < S_LEN / 128) {      // issue next-tile loads (hide under compute)
      k0r = *(const bf16x8*)pK;
      k1r = *(const bf16x8*)(pK + (size_t)64 * DM);
      v0r = *(const bf16x8*)pV;
      v1r = *(const bf16x8*)(pV + 64);
      n0 = pm[0]; n1 = pm[S_LEN];
      pK += (size_t)128 * DM; pV += 128; pm += 2 * S_LEN;
    }
    compute(&KVs[cur][0][0], &KVs[cur][2][0], m0);
    compute(&KVs[cur][1][0], &KVs[cur][3][0], m1);
    if (kt + 1 < S_LEN / 128) {      // write-late into the other buffer
      *(bf16x8*)&KVs[cur ^ 1][0][t * 8] = k0r;
      *(bf16x8*)&KVs[cur ^ 1][1][t * 8] = k1r;
      *(bf16x8*)&KVs[cur ^ 1][2][t * 8] = v0r;
      *(bf16x8*)&KVs[cur ^ 1][3][t * 8] = v1r;
      m0 = n0; m1 = n1;
    }
    __syncthreads();                 // one barrier per 128 keys
  }

  // epilogue (wave-local): l = own half + partner half; transpose via LDS scratch
  const float lsum = l_lane + __shfl_xor(l_lane, 32);
  const float inv = 1.f / lsum;
  bf16_t* sc = &KVs[0][0][0] + (size_t)w * 2048;  // wave-private 32x64 region
  #pragma unroll
  for (int ot = 0; ot < 2; ++ot)
    #pragma unroll
    for (int r = 0; r < 16; ++r) {
      const int dv = 32 * ot + (r & 3) + 8 * (r >> 2) + 4 * h5;
      sc[sw_off(l31, dv)] = (__bf16)(O[ot][r] * inv);
    }
  const int erow = L >> 1, ecol = (L & 1) * 32;
  bf16_t* dst = &ctx[(size_t)(b * S_LEN + q0 + 32 * w + erow) * DM + h * DK + ecol];
  #pragma unroll
  for (int c8 = 0; c8 < 4; ++c8)
    *(bf16x8*)(dst + 8 * c8) = *(const bf16x8*)&sc[sw_off(erow, ecol + 8 * c8)];
}

extern "C" void kernel_launch(void* const* d_in, const int* in_sizes, int n_in,
                              void* d_out, int out_size, void* d_ws, size_t ws_size,
                              hipStream_t stream) {
  const float* q  = (const float*)d_in[0];
  const float* k  = (const float*)d_in[1];
  const float* v  = (const float*)d_in[2];
  const int* mask = (const int*)d_in[3];
  const float* Wq = (const float*)d_in[4];
  const float* bq = (const float*)d_in[5];
  const float* Wk = (const float*)d_in[6];
  const float* bk = (const float*)d_in[7];
  const float* Wv = (const float*)d_in[8];
  const float* bv = (const float*)d_in[9];
  const float* Wo = (const float*)d_in[10];
  const float* bo = (const float*)d_in[11];
  float* out = (float*)d_out;

  const size_t SLICE = (size_t)M_ROWS * DM;  // 4M elems
  bf16_t* Xb   = (bf16_t*)d_ws;              // 3 slices (24 MB); reused below
  bf16_t* QKVb = Xb + 3 * SLICE;             // Q,K slices; slice2 = Vtw
  bf16_t* Wt   = QKVb + 3 * SLICE;           // 4 MM (8 MB)
  u64* mbw     = (u64*)(Wt + (size_t)4 * DM * DM);  // 131072 u64 (1 MB)
  bf16_t* ctx  = Xb;                         // alias slice 0 (Xb dead after gemm_qkv)
  bf16_t* Vtw  = QKVb + 2 * SLICE;           // V slice region, written transposed

  prep<<<dim3(7680), dim3(256), 0, stream>>>(q, k, v, Xb, Wq, Wk, Wv, Wo, Wt,
                                             mask, mbw);
  gemm_qkv<<<dim3(768), dim3(256), 0, stream>>>(Xb, Wt, bq, bk, bv, QKVb, Vtw);
  attn_kernel<<<dim3(256), dim3(512), 0, stream>>>(QKVb, QKVb + SLICE, Vtw, mbw, ctx);
  gemm_out<<<dim3(512), dim3(256), 0, stream>>>(ctx, Wt + (size_t)3 * DM * DM, bo, out);
}